// Round 3
// baseline (299.688 us; speedup 1.0000x reference)
//
#include <hip/hip_runtime.h>
#include <stdint.h>

// NeiAttention: B=512, N=32, S=16, EF=64, NF=D=128, K=192. Tiles = B*N = 16384.
// v^T = W(128x192) . feat^T(192x16): W A-frags REGISTER-resident (96 VGPR = half
// of W per wave; 2-wave blocks split d). feat staged once/tile to LDS as B-frags.
// Bias folds out (softmax shift-invariance + sum(w)=1). 2 syncthreads/tile,
// ~40 DS ops/tile/wave, 12 waves/CU for latency hiding.

typedef __attribute__((ext_vector_type(8))) short short8;
typedef __attribute__((ext_vector_type(4))) float float4_t;
typedef __attribute__((ext_vector_type(4))) unsigned short ushort4_t;

#define NBLK 2048
#define TILES_PER_BLK 8   // 2048 blocks * 8 = 16384 tiles

__device__ __forceinline__ unsigned short f2bf(float f) {
    uint32_t u = __float_as_uint(f);
    u += 0x7fffu + ((u >> 16) & 1u);   // RNE
    return (unsigned short)(u >> 16);
}

// B-frag LDS offset (ushort units) for feat element (s, k):
// kstep q=k/32, owner lane = ((k%32)/8)*16 + s, j = k%8. (round-2-verified)
__device__ __forceinline__ int aoff(int s, int kc) {
    return (((kc >> 5) * 64) + (((kc & 31) >> 3) * 16) + s) * 8 + (kc & 7);
}

__global__ __launch_bounds__(128, 3) void nei_attn_kernel(
    const float* __restrict__ x,
    const float* __restrict__ rel,
    const float* __restrict__ node,
    const float* __restrict__ W,
    const float* __restrict__ bias,
    float* __restrict__ out)
{
    __shared__ __align__(16) unsigned short lds_f[6 * 64 * 8]; // 6 KB feat bf16 B-frags
    __shared__ __align__(16) float lds_v[16][132];             // v[s][d], 2-way-free banks
    __shared__ float lds_alpha[2][16];
    __shared__ float lds_w[2][16];

    const int t    = threadIdx.x;
    const int lane = t & 63;
    const int wv   = t >> 6;        // 0 or 1: d-half owner
    const int l15  = lane & 15;
    const int quad = lane >> 4;

    // ---- W A-fragments, loaded ONCE, register-resident (96 VGPR) ----
    // lane holds W[64*wv + dt*16 + l15][q*32 + quad*8 + j], dt=0..3, q=0..5
    short8 wfrag[4][6];
    #pragma unroll
    for (int dt = 0; dt < 4; ++dt) {
        const float* wr = W + (size_t)(64 * wv + dt * 16 + l15) * 192;
        #pragma unroll
        for (int q = 0; q < 6; ++q) {
            const float* p = wr + q * 32 + quad * 8;
            float4_t a = *(const float4_t*)p;
            float4_t b = *(const float4_t*)(p + 4);
            short8 f;
            f[0] = (short)f2bf(a.x); f[1] = (short)f2bf(a.y);
            f[2] = (short)f2bf(a.z); f[3] = (short)f2bf(a.w);
            f[4] = (short)f2bf(b.x); f[5] = (short)f2bf(b.y);
            f[6] = (short)f2bf(b.z); f[7] = (short)f2bf(b.w);
            wfrag[dt][q] = f;
        }
    }
    const float bias_l = bias[64 * wv + lane];  // out d = 64*wv + lane

    // staging: wave wv loads rows s = wv*8 + (lane&7); f4 cols fb + 8c, fb = lane>>3
    const int s_st = wv * 8 + (lane & 7);
    const int fb   = lane >> 3;
    int ao[6];
    #pragma unroll
    for (int c = 0; c < 6; ++c) ao[c] = aoff(s_st, (fb + 8 * c) * 4);

    int tile = blockIdx.x * TILES_PER_BLK;
    for (int it = 0; it < TILES_PER_BLK; ++it, ++tile) {
        // ---- load half feat tile (128 B contiguous per row per instr) ----
        float4_t ld[6];
        {
            const float4_t* rb = (const float4_t*)rel  + (size_t)tile * 256 + s_st * 16;
            const float4_t* nb = (const float4_t*)node + (size_t)tile * 512 + s_st * 32;
            ld[0] = rb[fb];      ld[1] = rb[fb + 8];
            ld[2] = nb[fb];      ld[3] = nb[fb + 8];
            ld[4] = nb[fb + 16]; ld[5] = nb[fb + 24];
        }
        // ---- cvt + stage to LDS B-frag layout ----
        #pragma unroll
        for (int c = 0; c < 6; ++c) {
            ushort4_t u;
            u[0] = f2bf(ld[c].x); u[1] = f2bf(ld[c].y);
            u[2] = f2bf(ld[c].z); u[3] = f2bf(ld[c].w);
            *(ushort4_t*)&lds_f[ao[c]] = u;
        }
        __syncthreads();   // (1) feat frags ready (no vmem outstanding: loads consumed)

        // x values this lane needs: x[tile*128 + 64wv + 16dt + 4quad .. +4]
        float4_t xv[4];
        #pragma unroll
        for (int dt = 0; dt < 4; ++dt)
            xv[dt] = *(const float4_t*)(x + (size_t)tile * 128 + 64 * wv + 16 * dt + 4 * quad);

        // ---- projection: v[d][s] for d in wave's 64 rows ----
        float4_t acc[4];
        #pragma unroll
        for (int dt = 0; dt < 4; ++dt) acc[dt] = (float4_t){0.f, 0.f, 0.f, 0.f};
        #pragma unroll
        for (int q = 0; q < 6; ++q) {
            short8 bfr = *(const short8*)&lds_f[(q * 64 + lane) * 8];
            #pragma unroll
            for (int dt = 0; dt < 4; ++dt)
                acc[dt] = __builtin_amdgcn_mfma_f32_16x16x32_bf16(wfrag[dt][q], bfr, acc[dt], 0, 0, 0);
        }
        // acc[dt][r] = v_raw[d = 64wv + 16dt + 4quad + r][s = l15]  (bias folded out)

        // ---- alpha half: sum_d x[d]*v[d][s=l15] over this wave's 64 d ----
        float ap = 0.f;
        #pragma unroll
        for (int dt = 0; dt < 4; ++dt)
            ap += xv[dt].x * acc[dt][0] + xv[dt].y * acc[dt][1]
                + xv[dt].z * acc[dt][2] + xv[dt].w * acc[dt][3];
        ap += __shfl_xor(ap, 16);
        ap += __shfl_xor(ap, 32);          // all lanes: alpha_half[s = l15]
        if (lane < 16) lds_alpha[wv][lane] = ap;

        // v -> LDS transpose buffer (wave-private rows; intra-wave ordering only)
        #pragma unroll
        for (int dt = 0; dt < 4; ++dt)
            *(float4_t*)&lds_v[l15][64 * wv + 16 * dt + 4 * quad] = acc[dt];

        __syncthreads();   // (2) alpha halves ready

        const float alpha = (ap + lds_alpha[1 - wv][l15]) * 0.08838834764831845f;
        float mx = alpha;
        mx = fmaxf(mx, __shfl_xor(mx, 1));
        mx = fmaxf(mx, __shfl_xor(mx, 2));
        mx = fmaxf(mx, __shfl_xor(mx, 4));
        mx = fmaxf(mx, __shfl_xor(mx, 8));
        const float e = __expf(alpha - mx);
        float den = e;
        den += __shfl_xor(den, 1);
        den += __shfl_xor(den, 2);
        den += __shfl_xor(den, 4);
        den += __shfl_xor(den, 8);
        const float wgt = e / den;         // weight for s = l15
        if (quad == 0) lds_w[wv][l15] = wgt;   // intra-wave publish

        // ---- out[d] = bias[d] + sum_s w[s]*v[s][d]; lane owns d = 64wv+lane ----
        const int md = 64 * wv + lane;
        float4_t w0 = *(const float4_t*)&lds_w[wv][0];
        float4_t w1 = *(const float4_t*)&lds_w[wv][4];
        float4_t w2 = *(const float4_t*)&lds_w[wv][8];
        float4_t w3 = *(const float4_t*)&lds_w[wv][12];
        float o = bias_l;
        o += w0.x * lds_v[0][md]  + w0.y * lds_v[1][md]
           + w0.z * lds_v[2][md]  + w0.w * lds_v[3][md];
        o += w1.x * lds_v[4][md]  + w1.y * lds_v[5][md]
           + w1.z * lds_v[6][md]  + w1.w * lds_v[7][md];
        o += w2.x * lds_v[8][md]  + w2.y * lds_v[9][md]
           + w2.z * lds_v[10][md] + w2.w * lds_v[11][md];
        o += w3.x * lds_v[12][md] + w3.y * lds_v[13][md]
           + w3.z * lds_v[14][md] + w3.w * lds_v[15][md];
        out[(size_t)tile * 128 + md] = o;
        // next tile's lds_f writes are safe: this tile's frag reads preceded sync (2)
    }
}

extern "C" void kernel_launch(void* const* d_in, const int* in_sizes, int n_in,
                              void* d_out, int out_size, void* d_ws, size_t ws_size,
                              hipStream_t stream) {
    const float* x    = (const float*)d_in[0];
    const float* rel  = (const float*)d_in[1];
    const float* node = (const float*)d_in[2];
    const float* W    = (const float*)d_in[3];
    const float* bias = (const float*)d_in[4];
    float* out = (float*)d_out;
    hipLaunchKernelGGL(nei_attn_kernel, dim3(NBLK), dim3(128), 0, stream,
                       x, rel, node, W, bias, out);
}